// Round 1
// baseline (147.673 us; speedup 1.0000x reference)
//
#include <hip/hip_runtime.h>
#include <hip/hip_bf16.h>
#include <math.h>

// Block-sparse local+strided causal attention, MI355X (gfx950).
// One workgroup per (head, q-block). 4 waves x 64 lanes; each wave owns a
// 16-row q stripe. bf16 MFMA 16x16x32 for QK^T and PV, fp32 online softmax.

#define NHEADS 16
#define HDIM   64
#define BSZ    64
#define NBLK   64
#define KP     72   // LDS pitch in bf16 elems (64 + 8 pad -> bank-conflict free)

typedef __attribute__((ext_vector_type(8))) short bf16x8;
typedef __attribute__((ext_vector_type(4))) float f32x4;

__device__ __forceinline__ short f2bf(float x) {
    union { float f; unsigned u; } c; c.f = x;
    unsigned u = c.u;
    // round-to-nearest-even fp32 -> bf16
    unsigned r = (u + 0x7FFFu + ((u >> 16) & 1u)) >> 16;
    return (short)r;
}

__global__ __launch_bounds__(256)
void bs_attn_kernel(const float* __restrict__ q, const float* __restrict__ kg,
                    const float* __restrict__ vg, float* __restrict__ out) {
    __shared__ short kl[BSZ * KP];   // K block, row-major [key][d]
    __shared__ short vt[HDIM * KP];  // V block, transposed [d][key]
    __shared__ short pl[BSZ * KP];   // P stripe scratch [qrow][key] (per-wave rows)

    const int h   = blockIdx.x & (NHEADS - 1);
    const int qi  = blockIdx.x >> 4;
    const int tid = threadIdx.x;
    const int wave = tid >> 6;
    const int lane = tid & 63;
    const int l16  = lane & 15;
    const int quad = lane >> 4;

    // ---- Q A-fragments (A[m=l16][k=quad*8+j]), wave stripe rows ----
    const int mrow = qi * BSZ + wave * 16 + l16;
    const float* qrow = q + ((size_t)(mrow * NHEADS + h)) * HDIM;
    bf16x8 a_q[2];
    #pragma unroll
    for (int kk = 0; kk < 2; ++kk) {
        const float* src = qrow + kk * 32 + quad * 8;
        float4 f0 = *(const float4*)(src);
        float4 f1 = *(const float4*)(src + 4);
        bf16x8 a;
        a[0]=f2bf(f0.x); a[1]=f2bf(f0.y); a[2]=f2bf(f0.z); a[3]=f2bf(f0.w);
        a[4]=f2bf(f1.x); a[5]=f2bf(f1.y); a[6]=f2bf(f1.z); a[7]=f2bf(f1.w);
        a_q[kk] = a;
    }

    f32x4 o_acc[4];
    #pragma unroll
    for (int i = 0; i < 4; ++i) o_acc[i] = (f32x4){0.f, 0.f, 0.f, 0.f};
    float m_run[4], l_run[4];
    #pragma unroll
    for (int r = 0; r < 4; ++r) { m_run[r] = -INFINITY; l_run[r] = 0.f; }

    const float kscale = 0.125f * 1.4426950408889634f; // sm_scale * log2(e)

    for (int jb = 0; jb <= qi; ++jb) {
        // layout: causal AND (local-8 OR (j + h*1 + 1) % 8 == 0)   [uniform]
        if (!(((qi - jb) < 8) || (((jb + h + 1) & 7) == 0))) continue;

        __syncthreads();
        // ---- stage K block (bf16, row-major, coalesced global reads) ----
        {
            int rg = tid >> 4;
            int cg = (tid & 15) * 4;
            #pragma unroll
            for (int it = 0; it < 4; ++it) {
                int r = it * 16 + rg;
                const float* src = kg + ((size_t)((jb * BSZ + r) * NHEADS + h)) * HDIM + cg;
                float4 f = *(const float4*)src;
                short4 b;
                b.x = f2bf(f.x); b.y = f2bf(f.y); b.z = f2bf(f.z); b.w = f2bf(f.w);
                *(short4*)&kl[r * KP + cg] = b;
            }
        }
        // ---- stage V block transposed: vt[d][key] ----
        {
            int key = tid & 63;
            int c0  = (tid >> 6) * 16;
            const float* src = vg + ((size_t)((jb * BSZ + key) * NHEADS + h)) * HDIM + c0;
            #pragma unroll
            for (int j0 = 0; j0 < 16; j0 += 4) {
                float4 f = *(const float4*)(src + j0);
                vt[(c0 + j0 + 0) * KP + key] = f2bf(f.x);
                vt[(c0 + j0 + 1) * KP + key] = f2bf(f.y);
                vt[(c0 + j0 + 2) * KP + key] = f2bf(f.z);
                vt[(c0 + j0 + 3) * KP + key] = f2bf(f.w);
            }
        }
        __syncthreads();

        // ---- S = Q K^T : 16x64 per wave; C layout col=l16(key) row=quad*4+reg ----
        f32x4 s[4];
        #pragma unroll
        for (int nt = 0; nt < 4; ++nt) s[nt] = (f32x4){0.f, 0.f, 0.f, 0.f};
        #pragma unroll
        for (int nt = 0; nt < 4; ++nt) {
            #pragma unroll
            for (int kk = 0; kk < 2; ++kk) {
                bf16x8 bfr = *(const bf16x8*)&kl[(nt * 16 + l16) * KP + kk * 32 + quad * 8];
                s[nt] = __builtin_amdgcn_mfma_f32_16x16x32_bf16(a_q[kk], bfr, s[nt], 0, 0, 0);
            }
        }

        // ---- scale + causal mask (only diagonal block is partial) ----
        const bool diag = (jb == qi);
        #pragma unroll
        for (int nt = 0; nt < 4; ++nt) {
            #pragma unroll
            for (int r = 0; r < 4; ++r) {
                float val = s[nt][r] * kscale;
                if (diag) {
                    int n = nt * 16 + l16;          // key within block
                    int m = wave * 16 + quad * 4 + r; // query within block
                    if (n > m) val = -INFINITY;
                }
                s[nt][r] = val;
            }
        }

        // ---- online softmax (rows live on reg index; reduce across 16 lanes) ----
        float alpha[4], rsum[4];
        #pragma unroll
        for (int r = 0; r < 4; ++r) {
            float mx = fmaxf(fmaxf(s[0][r], s[1][r]), fmaxf(s[2][r], s[3][r]));
            #pragma unroll
            for (int off = 1; off < 16; off <<= 1)
                mx = fmaxf(mx, __shfl_xor(mx, off));
            float mnew = fmaxf(m_run[r], mx);
            alpha[r] = exp2f(m_run[r] - mnew);  // 0 when m_run = -inf
            m_run[r] = mnew;
            rsum[r] = 0.f;
        }
        #pragma unroll
        for (int nt = 0; nt < 4; ++nt) {
            #pragma unroll
            for (int r = 0; r < 4; ++r) {
                float p = exp2f(s[nt][r] - m_run[r]);
                s[nt][r] = p;
                rsum[r] += p;
            }
        }
        #pragma unroll
        for (int r = 0; r < 4; ++r) {
            float rs = rsum[r];
            #pragma unroll
            for (int off = 1; off < 16; off <<= 1)
                rs += __shfl_xor(rs, off);
            l_run[r] = l_run[r] * alpha[r] + rs;
            #pragma unroll
            for (int nt = 0; nt < 4; ++nt)
                o_acc[nt][r] *= alpha[r];
        }

        // ---- P: C layout -> LDS -> A layout (wave-private rows, no barrier) ----
        #pragma unroll
        for (int nt = 0; nt < 4; ++nt)
            #pragma unroll
            for (int r = 0; r < 4; ++r)
                pl[(wave * 16 + quad * 4 + r) * KP + nt * 16 + l16] = f2bf(s[nt][r]);
        bf16x8 a_p[2];
        #pragma unroll
        for (int kk = 0; kk < 2; ++kk)
            a_p[kk] = *(const bf16x8*)&pl[(wave * 16 + l16) * KP + kk * 32 + quad * 8];

        // ---- O += P V  (B[k=key][n=d] from vt[d][key]) ----
        #pragma unroll
        for (int nt = 0; nt < 4; ++nt) {
            #pragma unroll
            for (int kk = 0; kk < 2; ++kk) {
                bf16x8 bfr = *(const bf16x8*)&vt[(nt * 16 + l16) * KP + kk * 32 + quad * 8];
                o_acc[nt] = __builtin_amdgcn_mfma_f32_16x16x32_bf16(a_p[kk], bfr, o_acc[nt], 0, 0, 0);
            }
        }
    }

    // ---- epilogue: O / l, store fp32 ----
    #pragma unroll
    for (int r = 0; r < 4; ++r) {
        float inv = 1.0f / l_run[r];
        int t = qi * BSZ + wave * 16 + quad * 4 + r;
        float* orow = out + ((size_t)(t * NHEADS + h)) * HDIM;
        #pragma unroll
        for (int nt = 0; nt < 4; ++nt)
            orow[nt * 16 + l16] = o_acc[nt][r] * inv;
    }
}

extern "C" void kernel_launch(void* const* d_in, const int* in_sizes, int n_in,
                              void* d_out, int out_size, void* d_ws, size_t ws_size,
                              hipStream_t stream) {
    const float* q = (const float*)d_in[0];
    const float* k = (const float*)d_in[1];
    const float* v = (const float*)d_in[2];
    // d_in[3] = cu_seqlens_k, fixed [0, 4096] for this problem
    float* out = (float*)d_out;
    dim3 grid(NHEADS * NBLK);  // 1024 workgroups: (head, q-block)
    dim3 block(256);
    bs_attn_kernel<<<grid, block, 0, stream>>>(q, k, v, out);
}